// Round 13
// baseline (1099.215 us; speedup 1.0000x reference)
//
#include <hip/hip_runtime.h>
#include <hip/hip_bf16.h>
#include <cstdint>
#include <cstddef>

typedef _Float16 f16x8 __attribute__((ext_vector_type(8)));
typedef _Float16 f16x4 __attribute__((ext_vector_type(4)));
typedef float    f32x4 __attribute__((ext_vector_type(4)));

#define AS1 __attribute__((address_space(1)))
#define AS3 __attribute__((address_space(3)))

static constexpr int B_SZ = 2, SEQ = 4096, D_MODEL = 2048;
static constexpr int D_INNER = 4096, D_STATE = 16, D_CONV = 4, DT_RANK = 128;
static constexpr int M_ROWS = B_SZ * SEQ;          // 8192
static constexpr int SSM_W  = DT_RANK + 2 * D_STATE; // 160
static constexpr int KSPLIT = 8, KSLICE = 512;     // x_proj split-K

// ---------------------------------------------------------------- fused conversions
__global__ __launch_bounds__(256) void k_cvt_all(
    const float* __restrict__ s0, const float* __restrict__ s1,
    const float* __restrict__ s2, const float* __restrict__ s3,
    const float* __restrict__ s4,
    _Float16* __restrict__ d0, _Float16* __restrict__ d1,
    _Float16* __restrict__ d2, _Float16* __restrict__ d3,
    _Float16* __restrict__ d4) {
    const int i = blockIdx.x * 256 + threadIdx.x;   // grid sized exactly: 10780672 vec4
    const float* s; _Float16* d; int off;
    if (i < 4194304)      { s = s0; d = d0; off = i; }
    else if (i < 8388608) { s = s1; d = d1; off = i - 4194304; }
    else if (i < 8552448) { s = s2; d = d2; off = i - 8388608; }
    else if (i < 8683520) { s = s3; d = d3; off = i - 8552448; }
    else                  { s = s4; d = d4; off = i - 8683520; }
    f32x4 v = ((const f32x4*)s)[off];
    f16x4 h;
    h[0] = (_Float16)v[0]; h[1] = (_Float16)v[1];
    h[2] = (_Float16)v[2]; h[3] = (_Float16)v[3];
    ((f16x4*)d)[off] = h;
}

// ---------------------------------------------------------------- 256x256 pipelined NT GEMM
// FROZEN at the R10-validated schedule: 274us in_proj, MfmaUtil 45%, 0 conflicts,
// no spills. 3 barriers/K-tile; counted lgkm(4); dbuf; stage kt+2 into current
// buffer at cross-wave drain points; vmcnt(8); XOR-swizzle; setprio on MFMA.
template <int EPI>
__global__ __launch_bounds__(512, 2) void k_gemm256p(
    const _Float16* __restrict__ A, const _Float16* __restrict__ Bm, int K, int nby,
    void* __restrict__ out0, void* __restrict__ out1, int ldc) {
    __shared__ _Float16 lA[2][256][64];   // 64KB
    __shared__ _Float16 lB[2][256][64];   // 64KB
    constexpr int LBUF  = 32768;          // bytes per buffer
    constexpr int LBUFH = 16384;          // halves per buffer

    const int tid = threadIdx.x, l = tid & 63, w = tid >> 6;
    const int fr = l & 15, fq = l >> 4;
    const int wrA = (w >> 2) * 128;       // wave M origin (0/128)
    const int wcB = (w & 3) * 64;         // wave N origin

    // bijective XCD chunk swizzle (gridDim.x % 8 == 0 at all call sites)
    const int nwg = gridDim.x, qq = nwg >> 3;
    const int id = (blockIdx.x & 7) * qq + (blockIdx.x >> 3);
    const int by = id % nby, bx = id / nby;
    const int tileM = by * 256, tileN = bx * 256;

    // staging: lane l covers row (l>>3), 16B slot (l&7); global col pre-swizzled
    const int rsub = l >> 3;
    const int gco  = ((l & 7) ^ rsub) << 3;
    // fragment-read swizzle bases: slot (fq ^ (row&7)), row&7 == fr&7
    const int swz0 = (fq ^ (fr & 7)) << 4;

    const char* cA = (const char*)lA;
    const char* cB = (const char*)lB;
    const int bA0 = (wrA + fr) * 128 + swz0;   // k-half 0 base (byte)
    const int bA1 = bA0 ^ 64;                  // k-half 1 (slot+4 <=> ^64)
    const int bB0 = (wcB + fr) * 128 + swz0;
    const int bB1 = bB0 ^ 64;

    // running global pointers + fixed LDS dests (u = h*2+i)
    const _Float16* pA[4];
    const _Float16* pB[4];
    _Float16* dA[4];
    _Float16* dB[4];
#pragma unroll
    for (int u = 0; u < 4; ++u) {
        const int brow = (u >> 1) * 128 + (w * 2 + (u & 1)) * 8;
        pA[u] = A  + (size_t)(tileM + brow + rsub) * K + gco;
        pB[u] = Bm + (size_t)(tileN + brow + rsub) * K + gco;
        dA[u] = &lA[0][brow][0];
        dB[u] = &lB[0][brow][0];
    }

    const int NK = K >> 6;

    f32x4 acc[8][4];
#pragma unroll
    for (int m = 0; m < 8; m++)
#pragma unroll
        for (int n = 0; n < 4; n++) acc[m][n] = (f32x4)0.f;

    // prologue: stage tiles 0 and 1 fully (tile-0's 8 loads issued first)
#pragma unroll
    for (int t = 0; t < 2; ++t) {
#pragma unroll
        for (int u = 0; u < 4; ++u)
            __builtin_amdgcn_global_load_lds((const AS1 void*)(pA[u] + t * 64),
                (AS3 void*)(dA[u] + t * LBUFH), 16, 0, 0);
#pragma unroll
        for (int u = 0; u < 4; ++u)
            __builtin_amdgcn_global_load_lds((const AS1 void*)(pB[u] + t * 64),
                (AS3 void*)(dB[u] + t * LBUFH), 16, 0, 0);
    }
#pragma unroll
    for (int u = 0; u < 4; ++u) { pA[u] += 128; pB[u] += 128; }   // -> tile 2
    asm volatile("s_waitcnt vmcnt(8)" ::: "memory");
    __builtin_amdgcn_s_barrier();

    f16x8 af[4][2], bf0[2][2], bf1[2][2];

#define MFMA_QUAD(MO, NO, BF)                                                        \
    __builtin_amdgcn_s_setprio(1);                                                   \
    _Pragma("unroll") for (int m = 0; m < 4; ++m)                                    \
    _Pragma("unroll") for (int n = 0; n < 2; ++n)                                    \
    _Pragma("unroll") for (int kk = 0; kk < 2; ++kk)                                 \
        acc[(MO) + m][(NO) + n] = __builtin_amdgcn_mfma_f32_16x16x32_f16(            \
            af[m][kk], BF[n][kk], acc[(MO) + m][(NO) + n], 0, 0, 0);                 \
    __builtin_amdgcn_s_setprio(0);

#define KTILE(BUF, KOFF, PF, DOEND)                                                  \
    /* issue all 16 frag reads: af-lo (8), bf0 (4), bf1 (4) -- in this order */      \
    _Pragma("unroll")                                                                \
    for (int m = 0; m < 4; ++m) {                                                    \
        af[m][0] = *(const f16x8*)(cA + (BUF) * LBUF + bA0 + m * 2048);              \
        af[m][1] = *(const f16x8*)(cA + (BUF) * LBUF + bA1 + m * 2048);              \
    }                                                                                \
    _Pragma("unroll")                                                                \
    for (int n = 0; n < 2; ++n) {                                                    \
        bf0[n][0] = *(const f16x8*)(cB + (BUF) * LBUF + bB0 + n * 2048);             \
        bf0[n][1] = *(const f16x8*)(cB + (BUF) * LBUF + bB1 + n * 2048);             \
    }                                                                                \
    _Pragma("unroll")                                                                \
    for (int n = 0; n < 2; ++n) {                                                    \
        bf1[n][0] = *(const f16x8*)(cB + (BUF) * LBUF + bB0 + (n + 2) * 2048);       \
        bf1[n][1] = *(const f16x8*)(cB + (BUF) * LBUF + bB1 + (n + 2) * 2048);       \
    }                                                                                \
    asm volatile("s_waitcnt lgkmcnt(4)" ::: "memory");  /* first 12 (af-lo,bf0) */   \
    __builtin_amdgcn_sched_barrier(0);                                               \
    MFMA_QUAD(0, 0, bf0)                                                             \
    asm volatile("s_waitcnt lgkmcnt(0)" ::: "memory");  /* bf1 done */               \
    __builtin_amdgcn_sched_barrier(0);                                               \
    MFMA_QUAD(0, 2, bf1)                                                             \
    __builtin_amdgcn_s_barrier();   /* (i) all waves' B reads drained */             \
    _Pragma("unroll")                                                                \
    for (int m = 0; m < 4; ++m) {                                                    \
        af[m][0] = *(const f16x8*)(cA + (BUF) * LBUF + bA0 + (m + 4) * 2048);        \
        af[m][1] = *(const f16x8*)(cA + (BUF) * LBUF + bA1 + (m + 4) * 2048);        \
    }                                                                                \
    if (PF) {                                                                        \
        _Pragma("unroll")                                                            \
        for (int u = 0; u < 4; ++u)                                                  \
            __builtin_amdgcn_global_load_lds((const AS1 void*)(pB[u] + (KOFF)),      \
                (AS3 void*)(dB[u] + (BUF) * LBUFH), 16, 0, 0);                       \
    }                                                                                \
    asm volatile("s_waitcnt lgkmcnt(0)" ::: "memory");  /* af-hi done */             \
    __builtin_amdgcn_sched_barrier(0);                                               \
    MFMA_QUAD(4, 0, bf0)                                                             \
    __builtin_amdgcn_s_barrier();   /* (ii) all waves' A reads drained */            \
    if (PF) {                                                                        \
        _Pragma("unroll")                                                            \
        for (int u = 0; u < 4; ++u)                                                  \
            __builtin_amdgcn_global_load_lds((const AS1 void*)(pA[u] + (KOFF)),      \
                (AS3 void*)(dA[u] + (BUF) * LBUFH), 16, 0, 0);                       \
    }                                                                                \
    MFMA_QUAD(4, 2, bf1)                                                             \
    if (DOEND) {                                                                     \
        if (PF) { asm volatile("s_waitcnt vmcnt(8)" ::: "memory"); }                 \
        else    { asm volatile("s_waitcnt vmcnt(0)" ::: "memory"); }                 \
        __builtin_amdgcn_s_barrier();   /* (iii) staged tile visible */              \
    }

    for (int kt = 0; kt < NK; kt += 2) {
        const bool pf0 = (kt + 2 < NK);
        const bool pf1 = (kt + 3 < NK);
        KTILE(0, 0, pf0, true)
        KTILE(1, 64, pf1, pf0)
#pragma unroll
        for (int u = 0; u < 4; ++u) { pA[u] += 128; pB[u] += 128; }
    }
#undef KTILE
#undef MFMA_QUAD

    // epilogue
#pragma unroll
    for (int m = 0; m < 8; ++m) {
#pragma unroll
        for (int n = 0; n < 4; ++n) {
            const int r0 = tileM + wrA + m * 16 + fq * 4;
            const int c  = tileN + wcB + n * 16 + fr;
#pragma unroll
            for (int q = 0; q < 4; ++q) {
                const float  v  = acc[m][n][q];
                const size_t mm = (size_t)(r0 + q);
                if (EPI == 0) {
                    if (c < D_INNER)
                        ((_Float16*)out0)[mm * D_INNER + c] = (_Float16)v;
                    else
                        ((_Float16*)out1)[mm * D_INNER + (c - D_INNER)] = (_Float16)v;
                } else {
                    ((float*)out0)[mm * ldc + c] = v;
                }
            }
        }
    }
}

// ---------------------------------------------------------------- 128-tile NT GEMM (small GEMMs)
// EPI 1: f32 store (ldc); EPI 2: softplus(v+bias[n]) -> f16 (ldc);
// EPI 3: f32 store + f16 copy c<DT_RANK -> out1;
// EPI 4: split-K partial f32 store (blockIdx.z owns a KSLICE-wide K-slice).
template <int BM, int BN, int EPI>
__global__ __launch_bounds__(256) void k_gemm_nt(
    const _Float16* __restrict__ A, const _Float16* __restrict__ Bm, int K,
    int lda, int ldb, void* __restrict__ out0, void* __restrict__ out1,
    const float* __restrict__ bias, int ldc) {
    __shared__ _Float16 a_lds[BM][32];
    __shared__ _Float16 b_lds[BN][32];
    constexpr int MR = BM / 32;
    constexpr int NR = BN / 32;
    const int tid  = threadIdx.x;
    const int lane = tid & 63;
    const int wid  = tid >> 6;
    const int wr = wid >> 1, wc = wid & 1;
    const int tileM = blockIdx.y * BM;
    const int tileN = blockIdx.x * BN;
    const int kz = (EPI == 4) ? blockIdx.z * KSLICE : 0;

    f32x4 acc[MR][NR];
    for (int i = 0; i < MR; i++)
        for (int j = 0; j < NR; j++) acc[i][j] = (f32x4)0.f;

    constexpr int IS_A = BM / 16;
    constexpr int IS_B = BN / 16;
    const int srow = lane >> 2;
    const int skof = (lane & 3) * 8;
    const int fr = lane & 15, fq = lane >> 4;

    for (int kk = 0; kk < K; kk += 32) {
        if (kk) __syncthreads();
        for (int is = wid; is < IS_A + IS_B; is += 4) {
            const bool isA = is < IS_A;
            const int  li  = isA ? is : is - IS_A;
            const int  row = li * 16 + srow;
            const _Float16* g =
                isA ? (A  + (size_t)(tileM + row) * lda + kz + kk + skof)
                    : (Bm + (size_t)(tileN + row) * ldb + kz + kk + skof);
            char* lp = ((char*)(isA ? &a_lds[0][0] : &b_lds[0][0])) + (size_t)li * 1024;
            __builtin_amdgcn_global_load_lds((const AS1 void*)g, (AS3 void*)lp, 16, 0, 0);
        }
        __syncthreads();

        f16x8 af[MR], bf[NR];
#pragma unroll
        for (int i = 0; i < MR; i++)
            af[i] = *(const f16x8*)&a_lds[wr * (BM / 2) + i * 16 + fr][fq * 8];
#pragma unroll
        for (int j = 0; j < NR; j++)
            bf[j] = *(const f16x8*)&b_lds[wc * (BN / 2) + j * 16 + fr][fq * 8];
#pragma unroll
        for (int i = 0; i < MR; i++)
#pragma unroll
            for (int j = 0; j < NR; j++)
                acc[i][j] = __builtin_amdgcn_mfma_f32_16x16x32_f16(af[i], bf[j], acc[i][j], 0, 0, 0);
    }

#pragma unroll
    for (int i = 0; i < MR; i++) {
#pragma unroll
        for (int j = 0; j < NR; j++) {
            const int r0 = tileM + wr * (BM / 2) + i * 16 + fq * 4;
            const int c  = tileN + wc * (BN / 2) + j * 16 + fr;
#pragma unroll
            for (int q = 0; q < 4; q++) {
                const float  v = acc[i][j][q];
                const size_t m = (size_t)(r0 + q);
                if (EPI == 1) {
                    ((float*)out0)[m * ldc + c] = v;
                } else if (EPI == 2) {
                    float x  = v + bias[c];
                    float sp = (x > 20.f) ? x : log1pf(__expf(x));
                    ((_Float16*)out0)[m * ldc + c] = (_Float16)sp;
                } else if (EPI == 3) {
                    ((float*)out0)[m * ldc + c] = v;
                    if (c < DT_RANK)
                        ((_Float16*)out1)[m * DT_RANK + c] = (_Float16)v;
                } else {  // EPI == 4: split-K partial
                    ((float*)out0)[(size_t)blockIdx.z * M_ROWS * SSM_W + m * ldc + c] = v;
                }
            }
        }
    }
}

// ---------------------------------------------------------------- split-K reduce (+ dtr extract)
__global__ __launch_bounds__(256) void k_xred(const float* __restrict__ pbuf,
                                              float* __restrict__ ssm,
                                              _Float16* __restrict__ dtr) {
    const int i = blockIdx.x * 256 + threadIdx.x;   // over 8192*160 (grid exact)
    const int m = i / SSM_W;
    const int c = i - m * SSM_W;
    float s = 0.f;
#pragma unroll
    for (int z = 0; z < KSPLIT; ++z)
        s += pbuf[(size_t)z * M_ROWS * SSM_W + i];
    ssm[i] = s;
    if (c < DT_RANK) dtr[(size_t)m * DT_RANK + c] = (_Float16)s;
}

// ---------------------------------------------------------------- depthwise conv + SiLU
__global__ __launch_bounds__(256) void k_conv_silu(const _Float16* __restrict__ x,
                                                   const float* __restrict__ w,
                                                   const float* __restrict__ bias,
                                                   _Float16* __restrict__ out) {
    const int idx = blockIdx.x * 256 + threadIdx.x;
    const int d4 = idx & (D_INNER / 4 - 1);
    const int t  = (idx >> 10) & (SEQ - 1);
    const int b  = idx >> 22;
    const int d  = d4 * 4;
    const size_t rowbase = (size_t)b * SEQ * D_INNER;

    f32x4 wv[4];
#pragma unroll
    for (int i = 0; i < 4; i++) wv[i] = ((const f32x4*)w)[d + i];

    float acc[4];
#pragma unroll
    for (int i = 0; i < 4; i++) acc[i] = bias[d + i];
#pragma unroll
    for (int k = 0; k < D_CONV; k++) {
        int ti = t - (D_CONV - 1) + k;
        if (ti < 0) continue;
        f16x4 xv = *(const f16x4*)&x[rowbase + (size_t)ti * D_INNER + d];
#pragma unroll
        for (int i = 0; i < 4; i++) acc[i] += (float)xv[i] * wv[i][k];
    }
    f16x4 o;
#pragma unroll
    for (int i = 0; i < 4; i++) {
        float v = acc[i];
        o[i] = (_Float16)(v / (1.f + __expf(-v)));
    }
    *(f16x4*)&out[rowbase + (size_t)t * D_INNER + d] = o;
}

// ---------------------------------------------------------------- chunked selective scan
// R13: 4-step batched t-loop (loads issued up front -> deep ILP under exp2/FMA).
template <int CH, typename ST>
__global__ __launch_bounds__(256) void k_scan_p1(const _Float16* __restrict__ delta_h,
                                                 const _Float16* __restrict__ xc,
                                                 const float* __restrict__ ssm,
                                                 const float* __restrict__ Aptr,
                                                 ST* __restrict__ Sbuf,
                                                 ST* __restrict__ Pbuf) {
    constexpr int NCH = SEQ / CH;
    constexpr float L2E = 1.44269504088896f;
    const int bid   = blockIdx.x;
    const int dg    = bid & 15;
    const int chunk = (bid >> 4) % NCH;
    const int b     = bid / (16 * NCH);
    const int d     = dg * 256 + threadIdx.x;

    __shared__ float bsh[CH][D_STATE];
    const size_t rb = (size_t)b * SEQ + (size_t)chunk * CH;
    for (int i = threadIdx.x; i < CH * D_STATE; i += 256) {
        int t = i >> 4, n = i & 15;
        bsh[t][n] = ssm[(rb + t) * SSM_W + DT_RANK + n];
    }
    __syncthreads();

    float a2[D_STATE];
#pragma unroll
    for (int n = 0; n < D_STATE; n++) a2[n] = Aptr[(size_t)d * D_STATE + n] * L2E;
    float st[D_STATE];
#pragma unroll
    for (int n = 0; n < D_STATE; n++) st[n] = 0.f;
    float dtsum = 0.f;

    for (int t = 0; t < CH; t += 4) {
        const size_t i0 = (rb + t) * D_INNER + d;
        float dtv[4], uv[4];
#pragma unroll
        for (int j = 0; j < 4; ++j) {
            dtv[j] = (float)delta_h[i0 + (size_t)j * D_INNER];
            uv[j]  = (float)xc[i0 + (size_t)j * D_INNER];
        }
#pragma unroll
        for (int j = 0; j < 4; ++j) {
            const float du = dtv[j] * uv[j];
            dtsum += dtv[j];
#pragma unroll
            for (int n = 0; n < D_STATE; n++) {
                float p = exp2f(dtv[j] * a2[n]);
                st[n] = st[n] * p + du * bsh[t + j][n];
            }
        }
    }
    const size_t ob = ((size_t)(b * NCH + chunk) * D_STATE) * D_INNER + d;
#pragma unroll
    for (int n = 0; n < D_STATE; n++) {
        Sbuf[ob + (size_t)n * D_INNER] = (ST)st[n];
        Pbuf[ob + (size_t)n * D_INNER] = (ST)exp2f(dtsum * a2[n]);
    }
}

template <int NCH, typename ST>
__global__ __launch_bounds__(256) void k_scan_p2(ST* __restrict__ Sbuf,
                                                 const ST* __restrict__ Pbuf) {
    const int id = blockIdx.x * 256 + threadIdx.x;
    const int d = id & (D_INNER - 1);
    const int n = (id >> 12) & 15;
    const int b = id >> 16;
    float h = 0.f;
    for (int c = 0; c < NCH; ++c) {
        const size_t off = ((size_t)((b * NCH + c) * D_STATE + n)) * D_INNER + d;
        const float Pv = (float)Pbuf[off];
        const float Sv = (float)Sbuf[off];
        Sbuf[off] = (ST)h;
        h = Pv * h + Sv;
    }
}

template <int CH, typename ST>
__global__ __launch_bounds__(256) void k_scan_p3(const _Float16* __restrict__ delta_h,
                                                 const _Float16* __restrict__ xc,
                                                 const float* __restrict__ ssm,
                                                 const _Float16* __restrict__ z,
                                                 const float* __restrict__ Aptr,
                                                 const float* __restrict__ Dptr,
                                                 const ST* __restrict__ Sbuf,
                                                 _Float16* __restrict__ y_out) {
    constexpr int NCH = SEQ / CH;
    constexpr float L2E = 1.44269504088896f;
    const int bid   = blockIdx.x;
    const int dg    = bid & 15;
    const int chunk = (bid >> 4) % NCH;
    const int b     = bid / (16 * NCH);
    const int d     = dg * 256 + threadIdx.x;

    __shared__ float bsh[CH][2 * D_STATE];
    const size_t rb = (size_t)b * SEQ + (size_t)chunk * CH;
    for (int i = threadIdx.x; i < CH * 2 * D_STATE; i += 256) {
        int t = i >> 5, j = i & 31;
        bsh[t][j] = ssm[(rb + t) * SSM_W + DT_RANK + j];
    }
    __syncthreads();

    float a2[D_STATE];
#pragma unroll
    for (int n = 0; n < D_STATE; n++) a2[n] = Aptr[(size_t)d * D_STATE + n] * L2E;
    const float Dd = Dptr[d];

    const size_t ob = ((size_t)(b * NCH + chunk) * D_STATE) * D_INNER + d;
    float st[D_STATE];
#pragma unroll
    for (int n = 0; n < D_STATE; n++) st[n] = (float)Sbuf[ob + (size_t)n * D_INNER];

    for (int t = 0; t < CH; t += 4) {
        const size_t i0 = (rb + t) * D_INNER + d;
        float dtv[4], uv[4], zv[4];
#pragma unroll
        for (int j = 0; j < 4; ++j) {
            dtv[j] = (float)delta_h[i0 + (size_t)j * D_INNER];
            uv[j]  = (float)xc[i0 + (size_t)j * D_INNER];
            zv[j]  = (float)z[i0 + (size_t)j * D_INNER];
        }
#pragma unroll
        for (int j = 0; j < 4; ++j) {
            const float du = dtv[j] * uv[j];
            float y = 0.f;
#pragma unroll
            for (int n = 0; n < D_STATE; n++) {
                float p = exp2f(dtv[j] * a2[n]);
                st[n] = st[n] * p + du * bsh[t + j][n];
                y += st[n] * bsh[t + j][D_STATE + n];
            }
            const float g = zv[j] / (1.f + __expf(-zv[j]));
            y_out[i0 + (size_t)j * D_INNER] = (_Float16)((y + uv[j] * Dd) * g);
        }
    }
}

// ---------------------------------------------------------------- serial scan (fallback)
__global__ __launch_bounds__(256) void k_scan(const _Float16* __restrict__ delta_h,
                                              const _Float16* __restrict__ xc,
                                              const float* __restrict__ ssm,
                                              const _Float16* __restrict__ z,
                                              const float* __restrict__ Aptr,
                                              const float* __restrict__ Dptr,
                                              _Float16* __restrict__ y_out) {
    const int b = blockIdx.x >> 4;
    const int d = (blockIdx.x & 15) * 256 + threadIdx.x;
    constexpr float L2E = 1.44269504088896f;
    float a2[D_STATE];
#pragma unroll
    for (int n = 0; n < D_STATE; n++) a2[n] = Aptr[(size_t)d * D_STATE + n] * L2E;
    const float Dd = Dptr[d];
    float st[D_STATE];
#pragma unroll
    for (int n = 0; n < D_STATE; n++) st[n] = 0.f;
    __shared__ float bc[128][32];
    const size_t rb = (size_t)b * SEQ;
    for (int tc = 0; tc < SEQ; tc += 128) {
        __syncthreads();
        for (int i = threadIdx.x; i < 128 * 32; i += 256) {
            int tl = i >> 5, j = i & 31;
            bc[tl][j] = ssm[(rb + tc + tl) * SSM_W + DT_RANK + j];
        }
        __syncthreads();
        for (int tl = 0; tl < 128; ++tl) {
            const size_t idx = (rb + tc + tl) * D_INNER + d;
            const float dt = (float)delta_h[idx];
            const float u  = (float)xc[idx];
            const float du = dt * u;
            float y = 0.f;
#pragma unroll
            for (int n = 0; n < D_STATE; n++) {
                float dA = exp2f(dt * a2[n]);
                st[n] = st[n] * dA + du * bc[tl][n];
                y += st[n] * bc[tl][D_STATE + n];
            }
            const float zv = (float)z[idx];
            const float g  = zv / (1.f + __expf(-zv));
            y_out[idx] = (_Float16)((y + u * Dd) * g);
        }
    }
}

// ---------------------------------------------------------------- launch helpers
template <int CH, typename ST>
static void launch_chunked_scan(const _Float16* delta_h, const _Float16* xc,
                                const float* ssm, const _Float16* z,
                                const float* Aptr, const float* Dptr,
                                ST* S, ST* P, _Float16* y, hipStream_t stream) {
    constexpr int NCH = SEQ / CH;
    k_scan_p1<CH, ST><<<B_SZ * NCH * 16, 256, 0, stream>>>(delta_h, xc, ssm, Aptr, S, P);
    k_scan_p2<NCH, ST><<<(B_SZ * 16 * D_INNER) / 256, 256, 0, stream>>>(S, P);
    k_scan_p3<CH, ST><<<B_SZ * NCH * 16, 256, 0, stream>>>(delta_h, xc, ssm, z, Aptr, Dptr, S, y);
}

// ---------------------------------------------------------------- launch
extern "C" void kernel_launch(void* const* d_in, const int* in_sizes, int n_in,
                              void* d_out, int out_size, void* d_ws, size_t ws_size,
                              hipStream_t stream) {
    const float* hs    = (const float*)d_in[0];
    const float* W_in  = (const float*)d_in[1];
    const float* convw = (const float*)d_in[2];
    const float* convb = (const float*)d_in[3];
    const float* W_x   = (const float*)d_in[4];
    const float* W_dt  = (const float*)d_in[5];
    const float* dtb   = (const float*)d_in[6];
    const float* Aptr  = (const float*)d_in[7];
    const float* Dptr  = (const float*)d_in[8];
    const float* W_out = (const float*)d_in[9];

    char* ws = (char*)d_ws;
    _Float16* hs_h    = (_Float16*)(ws + 0);          //  32MB, dead after GEMM1
    _Float16* Win_h   = (_Float16*)(ws + 33554432);   //  32MB, dead after GEMM1
    _Float16* y_h     = (_Float16*)(ws + 0);          //  64MB, aliases hs_h+Win_h
    _Float16* xraw    = (_Float16*)(ws + 67108864);   //  64MB, dead after conv
    float*    pbuf    = (float*)   (ws + 67108864);   //  42MB split-K partials (xraw-dead region)
    _Float16* delta_h = (_Float16*)(ws + 67108864);   //  64MB, written after pbuf is dead
    _Float16* xc      = (_Float16*)(ws + 134217728);  //  64MB
    float*    ssm     = (float*)   (ws + 201326592);  // 5.25MB
    _Float16* dtr     = (_Float16*)(ws + 206569472);  //   2MB
    _Float16* Wx_h    = (_Float16*)(ws + 208666624);  // 1.3MB
    _Float16* Wdt_h   = (_Float16*)(ws + 209977344);  //   1MB
    _Float16* Wout_h  = (_Float16*)(ws + 211025920);  //  16MB  (ends 227,803,136)
    _Float16* z_h     = (_Float16*)d_out;             // z parked in d_out (64MB)
    const size_t spbase = 227803136ull;               // S/P region appended here

    // fused conversions (1 launch; grid exactly covers 10,780,672 vec4 units)
    k_cvt_all<<<42112, 256, 0, stream>>>(hs, W_in, W_x, W_dt, W_out,
                                         hs_h, Win_h, Wx_h, Wdt_h, Wout_h);

    // in_proj: (8192 x 2048) x (8192 x 2048)^T -> x_raw | z   [256^2, R10 frozen]
    k_gemm256p<0><<<(M_ROWS / 256) * (2 * D_INNER / 256), 512, 0, stream>>>(
        hs_h, Win_h, D_MODEL, M_ROWS / 256, xraw, z_h, 0);

    // causal depthwise conv + SiLU
    k_conv_silu<<<(B_SZ * SEQ * (D_INNER / 4)) / 256, 256, 0, stream>>>(xraw, convw, convb, xc);

    // x_proj (split-K): 8 K-slices of 512 -> f32 partials -> reduce (+ dtr extract)
    k_gemm_nt<64, 32, 4><<<dim3(SSM_W / 32, M_ROWS / 64, KSPLIT), 256, 0, stream>>>(
        xc, Wx_h, KSLICE, D_INNER, D_INNER, pbuf, nullptr, nullptr, SSM_W);
    k_xred<<<(M_ROWS * SSM_W) / 256, 256, 0, stream>>>(pbuf, ssm, dtr);

    // delta: (8192 x 128) x (4096 x 128)^T + bias -> softplus -> f16
    k_gemm_nt<128, 128, 2><<<dim3(D_INNER / 128, M_ROWS / 128), 256, 0, stream>>>(
        dtr, Wdt_h, DT_RANK, DT_RANK, DT_RANK, delta_h, nullptr, dtb, D_INNER);

    // chunked selective scan (pick widest variant that fits ws)
    {
        const size_t e64  = (size_t)B_SZ * (SEQ / 64)  * D_STATE * D_INNER;
        const size_t e128 = (size_t)B_SZ * (SEQ / 128) * D_STATE * D_INNER;
        if (ws_size >= spbase + 2 * e64 * sizeof(float)) {
            float* S = (float*)(ws + spbase);
            float* P = S + e64;
            launch_chunked_scan<64, float>(delta_h, xc, ssm, z_h, Aptr, Dptr, S, P, y_h, stream);
        } else if (ws_size >= spbase + 2 * e128 * sizeof(float)) {
            float* S = (float*)(ws + spbase);
            float* P = S + e128;
            launch_chunked_scan<128, float>(delta_h, xc, ssm, z_h, Aptr, Dptr, S, P, y_h, stream);
        } else if (ws_size >= spbase + 2 * e128 * sizeof(_Float16)) {
            _Float16* S = (_Float16*)(ws + spbase);
            _Float16* P = S + e128;
            launch_chunked_scan<128, _Float16>(delta_h, xc, ssm, z_h, Aptr, Dptr, S, P, y_h, stream);
        } else {
            k_scan<<<B_SZ * (D_INNER / 256), 256, 0, stream>>>(delta_h, xc, ssm, z_h, Aptr, Dptr, y_h);
        }
    }

    // out_proj: (8192 x 4096) x (2048 x 4096)^T -> d_out (f32)   [256^2, R10 frozen]
    k_gemm256p<1><<<(M_ROWS / 256) * (D_MODEL / 256), 512, 0, stream>>>(
        y_h, Wout_h, D_INNER, M_ROWS / 256, d_out, nullptr, D_MODEL);
}

// Round 14
// 1059.987 us; speedup vs baseline: 1.0370x; 1.0370x over previous
//
#include <hip/hip_runtime.h>
#include <hip/hip_bf16.h>
#include <cstdint>
#include <cstddef>

typedef _Float16 f16x8 __attribute__((ext_vector_type(8)));
typedef _Float16 f16x4 __attribute__((ext_vector_type(4)));
typedef float    f32x4 __attribute__((ext_vector_type(4)));

#define AS1 __attribute__((address_space(1)))
#define AS3 __attribute__((address_space(3)))

static constexpr int B_SZ = 2, SEQ = 4096, D_MODEL = 2048;
static constexpr int D_INNER = 4096, D_STATE = 16, D_CONV = 4, DT_RANK = 128;
static constexpr int M_ROWS = B_SZ * SEQ;          // 8192
static constexpr int SSM_W  = DT_RANK + 2 * D_STATE; // 160

// ---------------------------------------------------------------- fused conversions (vec8)
// segments in vec8 units: hs 2097152 | W_in 2097152 | W_x 81920 | W_dt 65536 | W_out 1048576
__global__ __launch_bounds__(256) void k_cvt_all(
    const float* __restrict__ s0, const float* __restrict__ s1,
    const float* __restrict__ s2, const float* __restrict__ s3,
    const float* __restrict__ s4,
    _Float16* __restrict__ d0, _Float16* __restrict__ d1,
    _Float16* __restrict__ d2, _Float16* __restrict__ d3,
    _Float16* __restrict__ d4) {
    const int i = blockIdx.x * 256 + threadIdx.x;   // grid exact: 5390336 vec8
    const float* s; _Float16* d; int off;
    if (i < 2097152)      { s = s0; d = d0; off = i; }
    else if (i < 4194304) { s = s1; d = d1; off = i - 2097152; }
    else if (i < 4276224) { s = s2; d = d2; off = i - 4194304; }
    else if (i < 4341760) { s = s3; d = d3; off = i - 4276224; }
    else                  { s = s4; d = d4; off = i - 4341760; }
    f32x4 v0 = ((const f32x4*)s)[off * 2];
    f32x4 v1 = ((const f32x4*)s)[off * 2 + 1];
    f16x8 h;
    h[0] = (_Float16)v0[0]; h[1] = (_Float16)v0[1];
    h[2] = (_Float16)v0[2]; h[3] = (_Float16)v0[3];
    h[4] = (_Float16)v1[0]; h[5] = (_Float16)v1[1];
    h[6] = (_Float16)v1[2]; h[7] = (_Float16)v1[3];
    ((f16x8*)d)[off] = h;
}

// ---------------------------------------------------------------- 256x256 pipelined NT GEMM
// FROZEN at the R10-validated schedule: 274us in_proj, MfmaUtil 45%, 0 conflicts,
// no spills. 3 barriers/K-tile; counted lgkm(4); dbuf; stage kt+2 into current
// buffer at cross-wave drain points; vmcnt(8); XOR-swizzle; setprio on MFMA.
template <int EPI>
__global__ __launch_bounds__(512, 2) void k_gemm256p(
    const _Float16* __restrict__ A, const _Float16* __restrict__ Bm, int K, int nby,
    void* __restrict__ out0, void* __restrict__ out1, int ldc) {
    __shared__ _Float16 lA[2][256][64];   // 64KB
    __shared__ _Float16 lB[2][256][64];   // 64KB
    constexpr int LBUF  = 32768;          // bytes per buffer
    constexpr int LBUFH = 16384;          // halves per buffer

    const int tid = threadIdx.x, l = tid & 63, w = tid >> 6;
    const int fr = l & 15, fq = l >> 4;
    const int wrA = (w >> 2) * 128;       // wave M origin (0/128)
    const int wcB = (w & 3) * 64;         // wave N origin

    // bijective XCD chunk swizzle (gridDim.x % 8 == 0 at all call sites)
    const int nwg = gridDim.x, qq = nwg >> 3;
    const int id = (blockIdx.x & 7) * qq + (blockIdx.x >> 3);
    const int by = id % nby, bx = id / nby;
    const int tileM = by * 256, tileN = bx * 256;

    // staging: lane l covers row (l>>3), 16B slot (l&7); global col pre-swizzled
    const int rsub = l >> 3;
    const int gco  = ((l & 7) ^ rsub) << 3;
    // fragment-read swizzle bases: slot (fq ^ (row&7)), row&7 == fr&7
    const int swz0 = (fq ^ (fr & 7)) << 4;

    const char* cA = (const char*)lA;
    const char* cB = (const char*)lB;
    const int bA0 = (wrA + fr) * 128 + swz0;   // k-half 0 base (byte)
    const int bA1 = bA0 ^ 64;                  // k-half 1 (slot+4 <=> ^64)
    const int bB0 = (wcB + fr) * 128 + swz0;
    const int bB1 = bB0 ^ 64;

    // running global pointers + fixed LDS dests (u = h*2+i)
    const _Float16* pA[4];
    const _Float16* pB[4];
    _Float16* dA[4];
    _Float16* dB[4];
#pragma unroll
    for (int u = 0; u < 4; ++u) {
        const int brow = (u >> 1) * 128 + (w * 2 + (u & 1)) * 8;
        pA[u] = A  + (size_t)(tileM + brow + rsub) * K + gco;
        pB[u] = Bm + (size_t)(tileN + brow + rsub) * K + gco;
        dA[u] = &lA[0][brow][0];
        dB[u] = &lB[0][brow][0];
    }

    const int NK = K >> 6;

    f32x4 acc[8][4];
#pragma unroll
    for (int m = 0; m < 8; m++)
#pragma unroll
        for (int n = 0; n < 4; n++) acc[m][n] = (f32x4)0.f;

    // prologue: stage tiles 0 and 1 fully (tile-0's 8 loads issued first)
#pragma unroll
    for (int t = 0; t < 2; ++t) {
#pragma unroll
        for (int u = 0; u < 4; ++u)
            __builtin_amdgcn_global_load_lds((const AS1 void*)(pA[u] + t * 64),
                (AS3 void*)(dA[u] + t * LBUFH), 16, 0, 0);
#pragma unroll
        for (int u = 0; u < 4; ++u)
            __builtin_amdgcn_global_load_lds((const AS1 void*)(pB[u] + t * 64),
                (AS3 void*)(dB[u] + t * LBUFH), 16, 0, 0);
    }
#pragma unroll
    for (int u = 0; u < 4; ++u) { pA[u] += 128; pB[u] += 128; }   // -> tile 2
    asm volatile("s_waitcnt vmcnt(8)" ::: "memory");
    __builtin_amdgcn_s_barrier();

    f16x8 af[4][2], bf0[2][2], bf1[2][2];

#define MFMA_QUAD(MO, NO, BF)                                                        \
    __builtin_amdgcn_s_setprio(1);                                                   \
    _Pragma("unroll") for (int m = 0; m < 4; ++m)                                    \
    _Pragma("unroll") for (int n = 0; n < 2; ++n)                                    \
    _Pragma("unroll") for (int kk = 0; kk < 2; ++kk)                                 \
        acc[(MO) + m][(NO) + n] = __builtin_amdgcn_mfma_f32_16x16x32_f16(            \
            af[m][kk], BF[n][kk], acc[(MO) + m][(NO) + n], 0, 0, 0);                 \
    __builtin_amdgcn_s_setprio(0);

#define KTILE(BUF, KOFF, PF, DOEND)                                                  \
    /* issue all 16 frag reads: af-lo (8), bf0 (4), bf1 (4) -- in this order */      \
    _Pragma("unroll")                                                                \
    for (int m = 0; m < 4; ++m) {                                                    \
        af[m][0] = *(const f16x8*)(cA + (BUF) * LBUF + bA0 + m * 2048);              \
        af[m][1] = *(const f16x8*)(cA + (BUF) * LBUF + bA1 + m * 2048);              \
    }                                                                                \
    _Pragma("unroll")                                                                \
    for (int n = 0; n < 2; ++n) {                                                    \
        bf0[n][0] = *(const f16x8*)(cB + (BUF) * LBUF + bB0 + n * 2048);             \
        bf0[n][1] = *(const f16x8*)(cB + (BUF) * LBUF + bB1 + n * 2048);             \
    }                                                                                \
    _Pragma("unroll")                                                                \
    for (int n = 0; n < 2; ++n) {                                                    \
        bf1[n][0] = *(const f16x8*)(cB + (BUF) * LBUF + bB0 + (n + 2) * 2048);       \
        bf1[n][1] = *(const f16x8*)(cB + (BUF) * LBUF + bB1 + (n + 2) * 2048);       \
    }                                                                                \
    asm volatile("s_waitcnt lgkmcnt(4)" ::: "memory");  /* first 12 (af-lo,bf0) */   \
    __builtin_amdgcn_sched_barrier(0);                                               \
    MFMA_QUAD(0, 0, bf0)                                                             \
    asm volatile("s_waitcnt lgkmcnt(0)" ::: "memory");  /* bf1 done */               \
    __builtin_amdgcn_sched_barrier(0);                                               \
    MFMA_QUAD(0, 2, bf1)                                                             \
    __builtin_amdgcn_s_barrier();   /* (i) all waves' B reads drained */             \
    _Pragma("unroll")                                                                \
    for (int m = 0; m < 4; ++m) {                                                    \
        af[m][0] = *(const f16x8*)(cA + (BUF) * LBUF + bA0 + (m + 4) * 2048);        \
        af[m][1] = *(const f16x8*)(cA + (BUF) * LBUF + bA1 + (m + 4) * 2048);        \
    }                                                                                \
    if (PF) {                                                                        \
        _Pragma("unroll")                                                            \
        for (int u = 0; u < 4; ++u)                                                  \
            __builtin_amdgcn_global_load_lds((const AS1 void*)(pB[u] + (KOFF)),      \
                (AS3 void*)(dB[u] + (BUF) * LBUFH), 16, 0, 0);                       \
    }                                                                                \
    asm volatile("s_waitcnt lgkmcnt(0)" ::: "memory");  /* af-hi done */             \
    __builtin_amdgcn_sched_barrier(0);                                               \
    MFMA_QUAD(4, 0, bf0)                                                             \
    __builtin_amdgcn_s_barrier();   /* (ii) all waves' A reads drained */            \
    if (PF) {                                                                        \
        _Pragma("unroll")                                                            \
        for (int u = 0; u < 4; ++u)                                                  \
            __builtin_amdgcn_global_load_lds((const AS1 void*)(pA[u] + (KOFF)),      \
                (AS3 void*)(dA[u] + (BUF) * LBUFH), 16, 0, 0);                       \
    }                                                                                \
    MFMA_QUAD(4, 2, bf1)                                                             \
    if (DOEND) {                                                                     \
        if (PF) { asm volatile("s_waitcnt vmcnt(8)" ::: "memory"); }                 \
        else    { asm volatile("s_waitcnt vmcnt(0)" ::: "memory"); }                 \
        __builtin_amdgcn_s_barrier();   /* (iii) staged tile visible */              \
    }

    for (int kt = 0; kt < NK; kt += 2) {
        const bool pf0 = (kt + 2 < NK);
        const bool pf1 = (kt + 3 < NK);
        KTILE(0, 0, pf0, true)
        KTILE(1, 64, pf1, pf0)
#pragma unroll
        for (int u = 0; u < 4; ++u) { pA[u] += 128; pB[u] += 128; }
    }
#undef KTILE
#undef MFMA_QUAD

    // epilogue
#pragma unroll
    for (int m = 0; m < 8; ++m) {
#pragma unroll
        for (int n = 0; n < 4; ++n) {
            const int r0 = tileM + wrA + m * 16 + fq * 4;
            const int c  = tileN + wcB + n * 16 + fr;
#pragma unroll
            for (int q = 0; q < 4; ++q) {
                const float  v  = acc[m][n][q];
                const size_t mm = (size_t)(r0 + q);
                if (EPI == 0) {
                    if (c < D_INNER)
                        ((_Float16*)out0)[mm * D_INNER + c] = (_Float16)v;
                    else
                        ((_Float16*)out1)[mm * D_INNER + (c - D_INNER)] = (_Float16)v;
                } else {
                    ((float*)out0)[mm * ldc + c] = v;
                }
            }
        }
    }
}

// ---------------------------------------------------------------- 128-tile NT GEMM (small GEMMs)
// EPI 1: f32 store (ldc); EPI 2: softplus(v+bias[n]) -> f16 (ldc);
// EPI 3: f32 store (ldc) + f16 copy of cols c<DT_RANK into out1 (fused extract_dtr).
template <int BM, int BN, int EPI>
__global__ __launch_bounds__(256) void k_gemm_nt(
    const _Float16* __restrict__ A, const _Float16* __restrict__ Bm, int K,
    int lda, int ldb, void* __restrict__ out0, void* __restrict__ out1,
    const float* __restrict__ bias, int ldc) {
    __shared__ _Float16 a_lds[BM][32];
    __shared__ _Float16 b_lds[BN][32];
    constexpr int MR = BM / 32;
    constexpr int NR = BN / 32;
    const int tid  = threadIdx.x;
    const int lane = tid & 63;
    const int wid  = tid >> 6;
    const int wr = wid >> 1, wc = wid & 1;
    const int tileM = blockIdx.y * BM;
    const int tileN = blockIdx.x * BN;

    f32x4 acc[MR][NR];
    for (int i = 0; i < MR; i++)
        for (int j = 0; j < NR; j++) acc[i][j] = (f32x4)0.f;

    constexpr int IS_A = BM / 16;
    constexpr int IS_B = BN / 16;
    const int srow = lane >> 2;
    const int skof = (lane & 3) * 8;
    const int fr = lane & 15, fq = lane >> 4;

    for (int kk = 0; kk < K; kk += 32) {
        if (kk) __syncthreads();
        for (int is = wid; is < IS_A + IS_B; is += 4) {
            const bool isA = is < IS_A;
            const int  li  = isA ? is : is - IS_A;
            const int  row = li * 16 + srow;
            const _Float16* g =
                isA ? (A  + (size_t)(tileM + row) * lda + kk + skof)
                    : (Bm + (size_t)(tileN + row) * ldb + kk + skof);
            char* lp = ((char*)(isA ? &a_lds[0][0] : &b_lds[0][0])) + (size_t)li * 1024;
            __builtin_amdgcn_global_load_lds((const AS1 void*)g, (AS3 void*)lp, 16, 0, 0);
        }
        __syncthreads();

        f16x8 af[MR], bf[NR];
#pragma unroll
        for (int i = 0; i < MR; i++)
            af[i] = *(const f16x8*)&a_lds[wr * (BM / 2) + i * 16 + fr][fq * 8];
#pragma unroll
        for (int j = 0; j < NR; j++)
            bf[j] = *(const f16x8*)&b_lds[wc * (BN / 2) + j * 16 + fr][fq * 8];
#pragma unroll
        for (int i = 0; i < MR; i++)
#pragma unroll
            for (int j = 0; j < NR; j++)
                acc[i][j] = __builtin_amdgcn_mfma_f32_16x16x32_f16(af[i], bf[j], acc[i][j], 0, 0, 0);
    }

#pragma unroll
    for (int i = 0; i < MR; i++) {
#pragma unroll
        for (int j = 0; j < NR; j++) {
            const int r0 = tileM + wr * (BM / 2) + i * 16 + fq * 4;
            const int c  = tileN + wc * (BN / 2) + j * 16 + fr;
#pragma unroll
            for (int q = 0; q < 4; q++) {
                const float  v = acc[i][j][q];
                const size_t m = (size_t)(r0 + q);
                if (EPI == 1) {
                    ((float*)out0)[m * ldc + c] = v;
                } else if (EPI == 2) {
                    float x  = v + bias[c];
                    float sp = (x > 20.f) ? x : log1pf(__expf(x));
                    ((_Float16*)out0)[m * ldc + c] = (_Float16)sp;
                } else {  // EPI == 3
                    ((float*)out0)[m * ldc + c] = v;
                    if (c < DT_RANK)
                        ((_Float16*)out1)[m * DT_RANK + c] = (_Float16)v;
                }
            }
        }
    }
}

// ---------------------------------------------------------------- depthwise conv + SiLU
__global__ __launch_bounds__(256) void k_conv_silu(const _Float16* __restrict__ x,
                                                   const float* __restrict__ w,
                                                   const float* __restrict__ bias,
                                                   _Float16* __restrict__ out) {
    const int idx = blockIdx.x * 256 + threadIdx.x;
    const int d4 = idx & (D_INNER / 4 - 1);
    const int t  = (idx >> 10) & (SEQ - 1);
    const int b  = idx >> 22;
    const int d  = d4 * 4;
    const size_t rowbase = (size_t)b * SEQ * D_INNER;

    f32x4 wv[4];
#pragma unroll
    for (int i = 0; i < 4; i++) wv[i] = ((const f32x4*)w)[d + i];

    float acc[4];
#pragma unroll
    for (int i = 0; i < 4; i++) acc[i] = bias[d + i];
#pragma unroll
    for (int k = 0; k < D_CONV; k++) {
        int ti = t - (D_CONV - 1) + k;
        if (ti < 0) continue;
        f16x4 xv = *(const f16x4*)&x[rowbase + (size_t)ti * D_INNER + d];
#pragma unroll
        for (int i = 0; i < 4; i++) acc[i] += (float)xv[i] * wv[i][k];
    }
    f16x4 o;
#pragma unroll
    for (int i = 0; i < 4; i++) {
        float v = acc[i];
        o[i] = (_Float16)(v / (1.f + __expf(-v)));
    }
    *(f16x4*)&out[rowbase + (size_t)t * D_INNER + d] = o;
}

// ---------------------------------------------------------------- chunked selective scan
// 4-step batched t-loop; S/P stored as ST (f16 primary: halves phase traffic).
template <int CH, typename ST>
__global__ __launch_bounds__(256) void k_scan_p1(const _Float16* __restrict__ delta_h,
                                                 const _Float16* __restrict__ xc,
                                                 const float* __restrict__ ssm,
                                                 const float* __restrict__ Aptr,
                                                 ST* __restrict__ Sbuf,
                                                 ST* __restrict__ Pbuf) {
    constexpr int NCH = SEQ / CH;
    constexpr float L2E = 1.44269504088896f;
    const int bid   = blockIdx.x;
    const int dg    = bid & 15;
    const int chunk = (bid >> 4) % NCH;
    const int b     = bid / (16 * NCH);
    const int d     = dg * 256 + threadIdx.x;

    __shared__ float bsh[CH][D_STATE];
    const size_t rb = (size_t)b * SEQ + (size_t)chunk * CH;
    for (int i = threadIdx.x; i < CH * D_STATE; i += 256) {
        int t = i >> 4, n = i & 15;
        bsh[t][n] = ssm[(rb + t) * SSM_W + DT_RANK + n];
    }
    __syncthreads();

    float a2[D_STATE];
#pragma unroll
    for (int n = 0; n < D_STATE; n++) a2[n] = Aptr[(size_t)d * D_STATE + n] * L2E;
    float st[D_STATE];
#pragma unroll
    for (int n = 0; n < D_STATE; n++) st[n] = 0.f;
    float dtsum = 0.f;

    for (int t = 0; t < CH; t += 4) {
        const size_t i0 = (rb + t) * D_INNER + d;
        float dtv[4], uv[4];
#pragma unroll
        for (int j = 0; j < 4; ++j) {
            dtv[j] = (float)delta_h[i0 + (size_t)j * D_INNER];
            uv[j]  = (float)xc[i0 + (size_t)j * D_INNER];
        }
#pragma unroll
        for (int j = 0; j < 4; ++j) {
            const float du = dtv[j] * uv[j];
            dtsum += dtv[j];
#pragma unroll
            for (int n = 0; n < D_STATE; n++) {
                float p = exp2f(dtv[j] * a2[n]);
                st[n] = st[n] * p + du * bsh[t + j][n];
            }
        }
    }
    const size_t ob = ((size_t)(b * NCH + chunk) * D_STATE) * D_INNER + d;
#pragma unroll
    for (int n = 0; n < D_STATE; n++) {
        Sbuf[ob + (size_t)n * D_INNER] = (ST)st[n];
        Pbuf[ob + (size_t)n * D_INNER] = (ST)exp2f(dtsum * a2[n]);
    }
}

template <int NCH, typename ST>
__global__ __launch_bounds__(256) void k_scan_p2(ST* __restrict__ Sbuf,
                                                 const ST* __restrict__ Pbuf) {
    const int id = blockIdx.x * 256 + threadIdx.x;
    const int d = id & (D_INNER - 1);
    const int n = (id >> 12) & 15;
    const int b = id >> 16;
    float h = 0.f;
    for (int c = 0; c < NCH; ++c) {
        const size_t off = ((size_t)((b * NCH + c) * D_STATE + n)) * D_INNER + d;
        const float Pv = (float)Pbuf[off];
        const float Sv = (float)Sbuf[off];
        Sbuf[off] = (ST)h;
        h = Pv * h + Sv;
    }
}

template <int CH, typename ST>
__global__ __launch_bounds__(256) void k_scan_p3(const _Float16* __restrict__ delta_h,
                                                 const _Float16* __restrict__ xc,
                                                 const float* __restrict__ ssm,
                                                 const _Float16* __restrict__ z,
                                                 const float* __restrict__ Aptr,
                                                 const float* __restrict__ Dptr,
                                                 const ST* __restrict__ Sbuf,
                                                 _Float16* __restrict__ y_out) {
    constexpr int NCH = SEQ / CH;
    constexpr float L2E = 1.44269504088896f;
    const int bid   = blockIdx.x;
    const int dg    = bid & 15;
    const int chunk = (bid >> 4) % NCH;
    const int b     = bid / (16 * NCH);
    const int d     = dg * 256 + threadIdx.x;

    __shared__ float bsh[CH][2 * D_STATE];
    const size_t rb = (size_t)b * SEQ + (size_t)chunk * CH;
    for (int i = threadIdx.x; i < CH * 2 * D_STATE; i += 256) {
        int t = i >> 5, j = i & 31;
        bsh[t][j] = ssm[(rb + t) * SSM_W + DT_RANK + j];
    }
    __syncthreads();

    float a2[D_STATE];
#pragma unroll
    for (int n = 0; n < D_STATE; n++) a2[n] = Aptr[(size_t)d * D_STATE + n] * L2E;
    const float Dd = Dptr[d];

    const size_t ob = ((size_t)(b * NCH + chunk) * D_STATE) * D_INNER + d;
    float st[D_STATE];
#pragma unroll
    for (int n = 0; n < D_STATE; n++) st[n] = (float)Sbuf[ob + (size_t)n * D_INNER];

    for (int t = 0; t < CH; t += 4) {
        const size_t i0 = (rb + t) * D_INNER + d;
        float dtv[4], uv[4], zv[4];
#pragma unroll
        for (int j = 0; j < 4; ++j) {
            dtv[j] = (float)delta_h[i0 + (size_t)j * D_INNER];
            uv[j]  = (float)xc[i0 + (size_t)j * D_INNER];
            zv[j]  = (float)z[i0 + (size_t)j * D_INNER];
        }
#pragma unroll
        for (int j = 0; j < 4; ++j) {
            const float du = dtv[j] * uv[j];
            float y = 0.f;
#pragma unroll
            for (int n = 0; n < D_STATE; n++) {
                float p = exp2f(dtv[j] * a2[n]);
                st[n] = st[n] * p + du * bsh[t + j][n];
                y += st[n] * bsh[t + j][D_STATE + n];
            }
            const float g = zv[j] / (1.f + __expf(-zv[j]));
            y_out[i0 + (size_t)j * D_INNER] = (_Float16)((y + uv[j] * Dd) * g);
        }
    }
}

// ---------------------------------------------------------------- serial scan (fallback)
__global__ __launch_bounds__(256) void k_scan(const _Float16* __restrict__ delta_h,
                                              const _Float16* __restrict__ xc,
                                              const float* __restrict__ ssm,
                                              const _Float16* __restrict__ z,
                                              const float* __restrict__ Aptr,
                                              const float* __restrict__ Dptr,
                                              _Float16* __restrict__ y_out) {
    const int b = blockIdx.x >> 4;
    const int d = (blockIdx.x & 15) * 256 + threadIdx.x;
    constexpr float L2E = 1.44269504088896f;
    float a2[D_STATE];
#pragma unroll
    for (int n = 0; n < D_STATE; n++) a2[n] = Aptr[(size_t)d * D_STATE + n] * L2E;
    const float Dd = Dptr[d];
    float st[D_STATE];
#pragma unroll
    for (int n = 0; n < D_STATE; n++) st[n] = 0.f;
    __shared__ float bc[128][32];
    const size_t rb = (size_t)b * SEQ;
    for (int tc = 0; tc < SEQ; tc += 128) {
        __syncthreads();
        for (int i = threadIdx.x; i < 128 * 32; i += 256) {
            int tl = i >> 5, j = i & 31;
            bc[tl][j] = ssm[(rb + tc + tl) * SSM_W + DT_RANK + j];
        }
        __syncthreads();
        for (int tl = 0; tl < 128; ++tl) {
            const size_t idx = (rb + tc + tl) * D_INNER + d;
            const float dt = (float)delta_h[idx];
            const float u  = (float)xc[idx];
            const float du = dt * u;
            float y = 0.f;
#pragma unroll
            for (int n = 0; n < D_STATE; n++) {
                float dA = exp2f(dt * a2[n]);
                st[n] = st[n] * dA + du * bc[tl][n];
                y += st[n] * bc[tl][D_STATE + n];
            }
            const float zv = (float)z[idx];
            const float g  = zv / (1.f + __expf(-zv));
            y_out[idx] = (_Float16)((y + u * Dd) * g);
        }
    }
}

// ---------------------------------------------------------------- launch helpers
template <int CH, typename ST>
static void launch_chunked_scan(const _Float16* delta_h, const _Float16* xc,
                                const float* ssm, const _Float16* z,
                                const float* Aptr, const float* Dptr,
                                ST* S, ST* P, _Float16* y, hipStream_t stream) {
    constexpr int NCH = SEQ / CH;
    k_scan_p1<CH, ST><<<B_SZ * NCH * 16, 256, 0, stream>>>(delta_h, xc, ssm, Aptr, S, P);
    k_scan_p2<NCH, ST><<<(B_SZ * 16 * D_INNER) / 256, 256, 0, stream>>>(S, P);
    k_scan_p3<CH, ST><<<B_SZ * NCH * 16, 256, 0, stream>>>(delta_h, xc, ssm, z, Aptr, Dptr, S, y);
}

// ---------------------------------------------------------------- launch
extern "C" void kernel_launch(void* const* d_in, const int* in_sizes, int n_in,
                              void* d_out, int out_size, void* d_ws, size_t ws_size,
                              hipStream_t stream) {
    const float* hs    = (const float*)d_in[0];
    const float* W_in  = (const float*)d_in[1];
    const float* convw = (const float*)d_in[2];
    const float* convb = (const float*)d_in[3];
    const float* W_x   = (const float*)d_in[4];
    const float* W_dt  = (const float*)d_in[5];
    const float* dtb   = (const float*)d_in[6];
    const float* Aptr  = (const float*)d_in[7];
    const float* Dptr  = (const float*)d_in[8];
    const float* W_out = (const float*)d_in[9];

    char* ws = (char*)d_ws;
    _Float16* hs_h    = (_Float16*)(ws + 0);          //  32MB, dead after GEMM1
    _Float16* Win_h   = (_Float16*)(ws + 33554432);   //  32MB, dead after GEMM1
    _Float16* y_h     = (_Float16*)(ws + 0);          //  64MB, aliases hs_h+Win_h
    _Float16* xraw    = (_Float16*)(ws + 67108864);   //  64MB, dead after conv
    _Float16* delta_h = (_Float16*)(ws + 67108864);   //  64MB, aliases xraw
    _Float16* xc      = (_Float16*)(ws + 134217728);  //  64MB
    float*    ssm     = (float*)   (ws + 201326592);  // 5.25MB
    _Float16* dtr     = (_Float16*)(ws + 206569472);  //   2MB
    _Float16* Wx_h    = (_Float16*)(ws + 208666624);  // 1.3MB
    _Float16* Wdt_h   = (_Float16*)(ws + 209977344);  //   1MB
    _Float16* Wout_h  = (_Float16*)(ws + 211025920);  //  16MB  (ends 227,803,136)
    _Float16* z_h     = (_Float16*)d_out;             // z parked in d_out (64MB)
    const size_t spbase = 227803136ull;               // S/P region appended here

    // fused conversions (1 launch; grid exact: 5,390,336 vec8)
    k_cvt_all<<<21056, 256, 0, stream>>>(hs, W_in, W_x, W_dt, W_out,
                                         hs_h, Win_h, Wx_h, Wdt_h, Wout_h);

    // in_proj: (8192 x 2048) x (8192 x 2048)^T -> x_raw | z   [256^2, R10 frozen]
    k_gemm256p<0><<<(M_ROWS / 256) * (2 * D_INNER / 256), 512, 0, stream>>>(
        hs_h, Win_h, D_MODEL, M_ROWS / 256, xraw, z_h, 0);

    // causal depthwise conv + SiLU
    k_conv_silu<<<(B_SZ * SEQ * (D_INNER / 4)) / 256, 256, 0, stream>>>(xraw, convw, convb, xc);

    // x_proj: (8192 x 4096) x (160 x 4096)^T -> ssm (f32) + dtr (f16, fused extract)
    k_gemm_nt<64, 32, 3><<<dim3(SSM_W / 32, M_ROWS / 64), 256, 0, stream>>>(
        xc, Wx_h, D_INNER, D_INNER, D_INNER, ssm, dtr, nullptr, SSM_W);

    // delta: (8192 x 128) x (4096 x 128)^T + bias -> softplus -> f16
    k_gemm_nt<128, 128, 2><<<dim3(D_INNER / 128, M_ROWS / 128), 256, 0, stream>>>(
        dtr, Wdt_h, DT_RANK, DT_RANK, DT_RANK, delta_h, nullptr, dtb, D_INNER);

    // chunked selective scan (f16 S/P primary: halves phase traffic)
    {
        const size_t e64  = (size_t)B_SZ * (SEQ / 64)  * D_STATE * D_INNER;
        const size_t e128 = (size_t)B_SZ * (SEQ / 128) * D_STATE * D_INNER;
        if (ws_size >= spbase + 2 * e64 * sizeof(_Float16)) {
            _Float16* S = (_Float16*)(ws + spbase);
            _Float16* P = S + e64;
            launch_chunked_scan<64, _Float16>(delta_h, xc, ssm, z_h, Aptr, Dptr, S, P, y_h, stream);
        } else if (ws_size >= spbase + 2 * e128 * sizeof(_Float16)) {
            _Float16* S = (_Float16*)(ws + spbase);
            _Float16* P = S + e128;
            launch_chunked_scan<128, _Float16>(delta_h, xc, ssm, z_h, Aptr, Dptr, S, P, y_h, stream);
        } else {
            k_scan<<<B_SZ * (D_INNER / 256), 256, 0, stream>>>(delta_h, xc, ssm, z_h, Aptr, Dptr, y_h);
        }
    }

    // out_proj: (8192 x 4096) x (2048 x 4096)^T -> d_out (f32)   [256^2, R10 frozen]
    k_gemm256p<1><<<(M_ROWS / 256) * (D_MODEL / 256), 512, 0, stream>>>(
        y_h, Wout_h, D_INNER, M_ROWS / 256, d_out, nullptr, D_MODEL);
}